// Round 1
// baseline (854.724 us; speedup 1.0000x reference)
//
#include <hip/hip_runtime.h>
#include <hip/hip_bf16.h>

// ---------------------------------------------------------------------------
// HybridGATLSTM on MI355X.
// Structure:
//   lstm_pre (x3)  : parallel input-projection GEMM per layer (MFMA split-fp16)
//   lstm_rec (x3)  : single-block sequential recurrence, Whh in VGPRs as f16
//                    hi/lo fragments, h through LDS (XOR-swizzled)
//   gat            : 1536 blocks, one per (b,s) graph; attn2 -> d_out (100 MB)
//   head_partial / head_final : tiny MLP heads
// LSTM scratch lives in the attn2 region of d_out (GAT runs after LSTM).
// ---------------------------------------------------------------------------

typedef _Float16 half8 __attribute__((ext_vector_type(8)));
typedef float floatx4 __attribute__((ext_vector_type(4)));

#define LOG2E 1.44269504088896f

__device__ __forceinline__ float fast_exp(float x) {
    return __builtin_amdgcn_exp2f(x * LOG2E);
}
__device__ __forceinline__ float sigm(float x) {
    x = fminf(fmaxf(x, -30.f), 30.f);
    return __builtin_amdgcn_rcpf(1.f + __builtin_amdgcn_exp2f(-x * LOG2E));
}
__device__ __forceinline__ float tanhp(float x) {
    x = fminf(fmaxf(x, -15.f), 15.f);
    float e = __builtin_amdgcn_exp2f(-2.f * LOG2E * x);
    return (1.f - e) * __builtin_amdgcn_rcpf(1.f + e);
}
__device__ __forceinline__ void cvt_split(float v, _Float16& hi, _Float16& lo) {
    hi = (_Float16)v;
    lo = (_Float16)(v - (float)hi);
}

// Gate-row mapping: col-tile ct in [0,32). Octet g = ct>>1 covers hidden units
// [8g,8g+8). Even ct: cols 0..7 = i-gates, 8..15 = f-gates. Odd ct: g / o.
// Gate rows: i: r=hu, f: 128+hu, g: 256+hu, o: 384+hu.
__device__ __forceinline__ int rowmap(int ct, int sub) {
    int hu = ((ct >> 1) << 3) + (sub & 7);
    int second = sub >> 3;
    int base = (ct & 1) ? (second ? 384 : 256) : (second ? 128 : 0);
    return base + hu;
}

// ---------------------------------------------------------------------------
// LSTM input projection: Pre[t] = In_t(16x128) @ Wih^T(128x512) + (bih+bhh)
// Stored in MFMA D layout: Pre[((t*32+ct)*4+reg)*64 + lane]
// ---------------------------------------------------------------------------
__global__ __launch_bounds__(1024) void lstm_pre_kernel(
    const float* __restrict__ in, int stride_b, int stride_t,
    const float* __restrict__ Wih,
    const float* __restrict__ bih, const float* __restrict__ bhh,
    float* __restrict__ Pre)
{
    int t = blockIdx.x;
    int tid = threadIdx.x;
    int w = tid >> 6, lane = tid & 63, quad = lane >> 4, sub = lane & 15;

    // A fragments: A[m=sub(batch)][k = kc*32 + quad*8 + j], split hi/lo fp16
    half8 a_hi[4], a_lo[4];
    const float* arow = in + sub * stride_b + t * stride_t;
#pragma unroll
    for (int kc = 0; kc < 4; ++kc) {
        const float* p = arow + kc * 32 + quad * 8;
#pragma unroll
        for (int j = 0; j < 8; ++j) {
            _Float16 hi, lo; cvt_split(p[j], hi, lo);
            a_hi[kc][j] = hi; a_lo[kc][j] = lo;
        }
    }
#pragma unroll
    for (int tt = 0; tt < 2; ++tt) {
        int ct = 2 * w + tt;
        int r = rowmap(ct, sub);
        half8 b_hi[4], b_lo[4];
#pragma unroll
        for (int kc = 0; kc < 4; ++kc) {
            const float* p = Wih + r * 128 + kc * 32 + quad * 8;
#pragma unroll
            for (int j = 0; j < 8; ++j) {
                _Float16 hi, lo; cvt_split(p[j], hi, lo);
                b_hi[kc][j] = hi; b_lo[kc][j] = lo;
            }
        }
        floatx4 acc = {0.f, 0.f, 0.f, 0.f};
#pragma unroll
        for (int kc = 0; kc < 4; ++kc) {
            acc = __builtin_amdgcn_mfma_f32_16x16x32_f16(a_hi[kc], b_hi[kc], acc, 0, 0, 0);
            acc = __builtin_amdgcn_mfma_f32_16x16x32_f16(a_hi[kc], b_lo[kc], acc, 0, 0, 0);
            acc = __builtin_amdgcn_mfma_f32_16x16x32_f16(a_lo[kc], b_hi[kc], acc, 0, 0, 0);
        }
        float bias = bih[r] + bhh[r];
#pragma unroll
        for (int reg = 0; reg < 4; ++reg)
            Pre[((t * 32 + ct) * 4 + reg) * 64 + lane] = acc[reg] + bias;
    }
}

// ---------------------------------------------------------------------------
// LSTM recurrence: one block, 8 waves, each wave owns 4 col-tiles (= 2 hidden
// octets i/f + g/o). Whh resident in VGPRs as split-fp16 fragments.
// h state through LDS with XOR-swizzled 8-element groups (bank spread).
// ---------------------------------------------------------------------------
__global__ __launch_bounds__(512) void lstm_rec_kernel(
    const float* __restrict__ Whh,
    const float* __restrict__ Pre,
    float* __restrict__ Hseq,      // [96][16][128]
    float* __restrict__ xl_out)    // optional [16][128] copy of t=95
{
    __shared__ _Float16 hhi[2048];
    __shared__ _Float16 hlo[2048];
    int tid = threadIdx.x;
    int w = tid >> 6, lane = tid & 63, quad = lane >> 4, sub = lane & 15;
    bool lowhalf = (sub & 8) == 0;

    half8 whi[4][4], wlo[4][4];
#pragma unroll
    for (int tt = 0; tt < 4; ++tt) {
        int ct = 4 * w + tt;
        int r = rowmap(ct, sub);
#pragma unroll
        for (int kc = 0; kc < 4; ++kc) {
            const float* p = Whh + r * 128 + kc * 32 + quad * 8;
#pragma unroll
            for (int j = 0; j < 8; ++j) {
                _Float16 hi, lo; cvt_split(p[j], hi, lo);
                whi[tt][kc][j] = hi; wlo[tt][kc][j] = lo;
            }
        }
    }
    for (int i = tid; i < 2048; i += 512) {
        hhi[i] = (_Float16)0.f; hlo[i] = (_Float16)0.f;
    }
    float cst[4] = {0.f, 0.f, 0.f, 0.f};
    float cur[16];
#pragma unroll
    for (int tt = 0; tt < 4; ++tt)
#pragma unroll
        for (int reg = 0; reg < 4; ++reg)
            cur[tt * 4 + reg] = Pre[((4 * w + tt) * 4 + reg) * 64 + lane];
    __syncthreads();

    const half8* hhi8 = (const half8*)hhi;
    const half8* hlo8 = (const half8*)hlo;

    for (int t = 0; t < 96; ++t) {
        // A fragments for h_{t-1}: logical group g = kc*4+quad stored at g^sub
        half8 ahi[4], alo[4];
#pragma unroll
        for (int kc = 0; kc < 4; ++kc) {
            int g = ((kc * 4 + quad) ^ sub) & 15;
            ahi[kc] = hhi8[sub * 16 + g];
            alo[kc] = hlo8[sub * 16 + g];
        }
        floatx4 acc[4];
#pragma unroll
        for (int tt = 0; tt < 4; ++tt) {
            floatx4 a = {cur[tt * 4 + 0], cur[tt * 4 + 1], cur[tt * 4 + 2], cur[tt * 4 + 3]};
            acc[tt] = a;
        }
        // prefetch next timestep's Pre while MFMAs run
        float nxt[16];
        if (t < 95) {
#pragma unroll
            for (int tt = 0; tt < 4; ++tt)
#pragma unroll
                for (int reg = 0; reg < 4; ++reg)
                    nxt[tt * 4 + reg] =
                        Pre[(((t + 1) * 32 + 4 * w + tt) * 4 + reg) * 64 + lane];
        }
#pragma unroll
        for (int tt = 0; tt < 4; ++tt) {
#pragma unroll
            for (int kc = 0; kc < 4; ++kc) {
                acc[tt] = __builtin_amdgcn_mfma_f32_16x16x32_f16(ahi[kc], whi[tt][kc], acc[tt], 0, 0, 0);
                acc[tt] = __builtin_amdgcn_mfma_f32_16x16x32_f16(ahi[kc], wlo[tt][kc], acc[tt], 0, 0, 0);
                acc[tt] = __builtin_amdgcn_mfma_f32_16x16x32_f16(alo[kc], whi[tt][kc], acc[tt], 0, 0, 0);
            }
        }
        __syncthreads();  // all LDS h reads for this step complete

        // activations: lane sub<8 handles batch regs {0,1}, sub>=8 regs {2,3};
        // i/f and g/o for the same hidden unit live in partner lanes (xor 8)
#pragma unroll
        for (int p = 0; p < 2; ++p) {
            floatx4 IF = acc[2 * p], GO = acc[2 * p + 1];
            int hu = 16 * w + 8 * p + (sub & 7);
            int grp = 2 * w + p;  // hu >> 3
#pragma unroll
            for (int r2 = 0; r2 < 2; ++r2) {
                float my_if = lowhalf ? IF[r2] : IF[2 + r2];
                float my_go = lowhalf ? GO[r2] : GO[2 + r2];
                float sd_if = lowhalf ? IF[2 + r2] : IF[r2];  // what partner needs
                float sd_go = lowhalf ? GO[2 + r2] : GO[r2];
                float ot_if = __shfl_xor(sd_if, 8, 64);
                float ot_go = __shfl_xor(sd_go, 8, 64);
                float gi = lowhalf ? my_if : ot_if;
                float gf = lowhalf ? ot_if : my_if;
                float gg = lowhalf ? my_go : ot_go;
                float go = lowhalf ? ot_go : my_go;
                float si = sigm(gi), sf = sigm(gf), so = sigm(go);
                float tg = tanhp(gg);
                float c = sf * cst[p * 2 + r2] + si * tg;
                cst[p * 2 + r2] = c;
                float h = so * tanhp(c);
                int b = quad * 4 + (lowhalf ? r2 : 2 + r2);
                _Float16 hh, hl; cvt_split(h, hh, hl);
                int lidx = b * 128 + (((grp ^ b) & 15) << 3) + (hu & 7);
                hhi[lidx] = hh; hlo[lidx] = hl;
                Hseq[t * 2048 + b * 128 + hu] = h;
                if (xl_out != nullptr && t == 95) xl_out[b * 128 + hu] = h;
            }
        }
        __syncthreads();  // new h visible before next step's reads
        if (t < 95) {
#pragma unroll
            for (int i2 = 0; i2 < 16; ++i2) cur[i2] = nxt[i2];
        }
    }
}

// ---------------------------------------------------------------------------
// GAT: one block per graph m = b*96+s. Uses the FI=1 collapse:
// Wh1[n,f] = x[n]*u1[f]+v1[f]; GAT1 reduces to scalar s1[i].
// Writes attn2 (128x128) to d_out; out2 only for s==95 graphs.
// ---------------------------------------------------------------------------
__global__ __launch_bounds__(256) void gat_kernel(
    const float* __restrict__ x, const float* __restrict__ adj,
    const float* __restrict__ W_emb, const float* __restrict__ b_emb,
    const float* __restrict__ W1, const float* __restrict__ a1,
    const float* __restrict__ W2, const float* __restrict__ a2,
    float* __restrict__ attn_out, float* __restrict__ xg)
{
    int m = blockIdx.x;
    int tid = threadIdx.x;
    __shared__ float xv[128];
    __shared__ unsigned char adjb[128 * 132];
    __shared__ float u1[32], v1[32];
    __shared__ float coef[4];
    __shared__ float s1v[128];
    __shared__ float h2s[128 * 33];
    __shared__ float wh2[128 * 17];
    __shared__ float Lv[128], Rv[128], mx2[128], rd2[128];
    __shared__ float m_h[2][128], d_h[2][128], s_h[2][128];

    if (tid < 128) xv[tid] = x[m * 128 + tid];
    for (int idx = tid; idx < 16384; idx += 256) {
        int i = idx >> 7, j = idx & 127;
        adjb[i * 132 + j] = adj[idx] > 0.f ? 1 : 0;
    }
    if (tid < 32) {
        float su = 0.f, sv = 0.f;
        for (int kk = 0; kk < 32; ++kk) {
            su += W_emb[kk] * W1[kk * 32 + tid];
            sv += b_emb[kk] * W1[kk * 32 + tid];
        }
        u1[tid] = su; v1[tid] = sv;
    }
    __syncthreads();
    if (tid < 4) {
        const float* av = a1 + ((tid >= 2) ? 32 : 0);
        const float* uv = (tid & 1) ? v1 : u1;
        float s = 0.f;
        for (int f = 0; f < 32; ++f) s += uv[f] * av[f];
        coef[tid] = s;  // 0:cL 1:dL 2:cR 3:dR
    }
    __syncthreads();
    float cL = coef[0], dL = coef[1], cR = coef[2], dR = coef[3];

    // GAT1 softmax stats + weighted scalar sum, thread = (row i, half hf)
    {
        int i = tid & 127, hf = tid >> 7;
        float Li = xv[i] * cL + dL;
        int j0 = hf * 64;
        float mmax = -3.0e38f;
        for (int j = j0; j < j0 + 64; ++j) {
            if (adjb[i * 132 + j]) {
                float e = Li + xv[j] * cR + dR;
                e = e > 0.f ? e : 0.2f * e;
                mmax = fmaxf(mmax, e);
            }
        }
        float den = 0.f, wsum = 0.f;
        for (int j = j0; j < j0 + 64; ++j) {
            if (adjb[i * 132 + j]) {
                float e = Li + xv[j] * cR + dR;
                e = e > 0.f ? e : 0.2f * e;
                float p = fast_exp(e - mmax);
                den += p; wsum += p * xv[j];
            }
        }
        m_h[hf][i] = mmax; d_h[hf][i] = den; s_h[hf][i] = wsum;
    }
    __syncthreads();
    if (tid < 128) {
        int i = tid;
        float m0 = m_h[0][i], m1 = m_h[1][i];
        float mm = fmaxf(m0, m1);
        float sc0 = fast_exp(m0 - mm), sc1 = fast_exp(m1 - mm);
        float den = d_h[0][i] * sc0 + d_h[1][i] * sc1;
        float wsum = s_h[0][i] * sc0 + s_h[1][i] * sc1;
        s1v[i] = wsum / den;
    }
    __syncthreads();
    // h2 = elu(s1*u1 + v1)
    for (int e = tid; e < 4096; e += 256) {
        int i = e >> 5, f = e & 31;
        float v = s1v[i] * u1[f] + v1[f];
        h2s[i * 33 + f] = v > 0.f ? v : fast_exp(v) - 1.f;
    }
    __syncthreads();
    // Wh2 = h2 @ W2 (128x32 @ 32x16)
    {
        int i = tid >> 1, g0 = (tid & 1) * 8;
        float accv[8] = {0.f, 0.f, 0.f, 0.f, 0.f, 0.f, 0.f, 0.f};
        for (int f = 0; f < 32; ++f) {
            float hv = h2s[i * 33 + f];
#pragma unroll
            for (int g = 0; g < 8; ++g) accv[g] += hv * W2[f * 16 + g0 + g];
        }
#pragma unroll
        for (int g = 0; g < 8; ++g) wh2[i * 17 + g0 + g] = accv[g];
    }
    __syncthreads();
    {
        int i = tid & 127, which = tid >> 7;
        const float* aa = a2 + which * 16;
        float s = 0.f;
        for (int g = 0; g < 16; ++g) s += wh2[i * 17 + g] * aa[g];
        (which ? Rv : Lv)[i] = s;
    }
    __syncthreads();
    // attn2 softmax stats
    {
        int i = tid & 127, hf = tid >> 7;
        float Li = Lv[i];
        int j0 = hf * 64;
        float mmax = -3.0e38f;
        for (int j = j0; j < j0 + 64; ++j) {
            if (adjb[i * 132 + j]) {
                float e = Li + Rv[j];
                e = e > 0.f ? e : 0.2f * e;
                mmax = fmaxf(mmax, e);
            }
        }
        float den = 0.f;
        for (int j = j0; j < j0 + 64; ++j) {
            if (adjb[i * 132 + j]) {
                float e = Li + Rv[j];
                e = e > 0.f ? e : 0.2f * e;
                den += fast_exp(e - mmax);
            }
        }
        m_h[hf][i] = mmax; d_h[hf][i] = den;
    }
    __syncthreads();
    if (tid < 128) {
        int i = tid;
        float m0 = m_h[0][i], m1 = m_h[1][i];
        float mm = fmaxf(m0, m1);
        float den = d_h[0][i] * fast_exp(m0 - mm) + d_h[1][i] * fast_exp(m1 - mm);
        mx2[i] = mm; rd2[i] = 1.0f / den;
    }
    __syncthreads();
    // coalesced attn2 write
    float* aout = attn_out + m * 16384;
    for (int idx = tid; idx < 16384; idx += 256) {
        int i = idx >> 7, j = idx & 127;
        float p = 0.f;
        if (adjb[i * 132 + j]) {
            float e = Lv[i] + Rv[j];
            e = e > 0.f ? e : 0.2f * e;
            p = fast_exp(e - mx2[i]) * rd2[i];
        }
        aout[idx] = p;
    }
    // out2 = attn2 @ Wh2 only for the last timestep of each batch
    if (m % 96 == 95) {
        int b = m / 96;
        int i = tid >> 1, g0 = (tid & 1) * 8;
        float accv[8] = {0.f, 0.f, 0.f, 0.f, 0.f, 0.f, 0.f, 0.f};
        for (int j = 0; j < 128; ++j) {
            float p = 0.f;
            if (adjb[i * 132 + j]) {
                float e = Lv[i] + Rv[j];
                e = e > 0.f ? e : 0.2f * e;
                p = fast_exp(e - mx2[i]) * rd2[i];
            }
#pragma unroll
            for (int g = 0; g < 8; ++g) accv[g] += p * wh2[j * 17 + g0 + g];
        }
#pragma unroll
        for (int g = 0; g < 8; ++g) xg[b * 2048 + i * 16 + g0 + g] = accv[g];
    }
}

// ---------------------------------------------------------------------------
// Heads: h1 = relu(c @ W1[k] + b1), K split into 16 chunks for parallelism
// ---------------------------------------------------------------------------
__global__ __launch_bounds__(256) void head_partial_kernel(
    const float* __restrict__ xl, const float* __restrict__ xg,
    const float* __restrict__ W1, float* __restrict__ hp)
{
    int k = blockIdx.x >> 4, chunk = blockIdx.x & 15;
    int d = threadIdx.x & 63, bg = threadIdx.x >> 6;
    float acc[4] = {0.f, 0.f, 0.f, 0.f};
    int c0 = chunk * 136;
    for (int cc = c0; cc < c0 + 136; ++cc) {
        float wv = W1[(k * 2176 + cc) * 64 + d];
#pragma unroll
        for (int u = 0; u < 4; ++u) {
            int b = bg * 4 + u;
            float cv = (cc < 128) ? xl[b * 128 + cc] : xg[b * 2048 + cc - 128];
            acc[u] += wv * cv;
        }
    }
#pragma unroll
    for (int u = 0; u < 4; ++u)
        hp[(((k * 16 + chunk) * 16) + bg * 4 + u) * 64 + d] = acc[u];
}

__global__ __launch_bounds__(256) void head_final_kernel(
    const float* __restrict__ hp, const float* __restrict__ b1,
    const float* __restrict__ W2, const float* __restrict__ b2,
    const float* __restrict__ W3d, const float* __restrict__ b3d,
    const float* __restrict__ W3r, const float* __restrict__ b3r,
    const float* __restrict__ W3v, const float* __restrict__ b3v,
    float* __restrict__ out)
{
    __shared__ float h1s[3 * 16 * 64];
    __shared__ float h2s[3 * 16 * 32];
    int tid = threadIdx.x;
    for (int o = tid; o < 3072; o += 256) {
        int k = o >> 10, rem = o & 1023, b = rem >> 6, d = rem & 63;
        float s = b1[k * 64 + d];
        for (int ch = 0; ch < 16; ++ch)
            s += hp[(((k * 16 + ch) * 16) + b) * 64 + d];
        h1s[o] = fmaxf(s, 0.f);
    }
    __syncthreads();
    for (int o = tid; o < 1536; o += 256) {
        int k = o >> 9, rem = o & 511, b = rem >> 5, e = rem & 31;
        float s = b2[k * 32 + e];
        for (int dd = 0; dd < 64; ++dd)
            s += h1s[(k * 16 + b) * 64 + dd] * W2[(k * 64 + dd) * 32 + e];
        h2s[o] = fmaxf(s, 0.f);
    }
    __syncthreads();
    if (tid < 64) {
        if (tid < 16) {
            int b = tid; float s = b3d[0];
            for (int e = 0; e < 32; ++e) s += h2s[b * 32 + e] * W3d[e];
            out[b] = s;
        } else if (tid < 32) {
            int b = tid - 16; float s = b3r[0];
            for (int e = 0; e < 32; ++e) s += h2s[(16 + b) * 32 + e] * W3r[e];
            out[16 + b] = s;
        } else {
            int b = (tid - 32) >> 1, j = tid & 1; float s = b3v[j];
            for (int e = 0; e < 32; ++e) s += h2s[(32 + b) * 32 + e] * W3v[e * 2 + j];
            out[32 + b * 2 + j] = s;
        }
    }
}

// ---------------------------------------------------------------------------
extern "C" void kernel_launch(void* const* d_in, const int* in_sizes, int n_in,
                              void* d_out, int out_size, void* d_ws, size_t ws_size,
                              hipStream_t stream)
{
    const float* x     = (const float*)d_in[0];
    const float* adj   = (const float*)d_in[1];
    const float* W_emb = (const float*)d_in[2];
    const float* b_emb = (const float*)d_in[3];
    const float* W1    = (const float*)d_in[4];
    const float* a1    = (const float*)d_in[5];
    const float* W2    = (const float*)d_in[6];
    const float* a2    = (const float*)d_in[7];
    const float* Wih   = (const float*)d_in[8];
    const float* Whh   = (const float*)d_in[9];
    const float* bih   = (const float*)d_in[10];
    const float* bhh   = (const float*)d_in[11];
    const float* hW1   = (const float*)d_in[12];
    const float* hb1   = (const float*)d_in[13];
    const float* hW2   = (const float*)d_in[14];
    const float* hb2   = (const float*)d_in[15];
    const float* W3d   = (const float*)d_in[16];
    const float* b3d   = (const float*)d_in[17];
    const float* W3r   = (const float*)d_in[18];
    const float* b3r   = (const float*)d_in[19];
    const float* W3v   = (const float*)d_in[20];
    const float* b3v   = (const float*)d_in[21];

    float* out = (float*)d_out;
    // attn2 region of d_out doubles as LSTM scratch (GAT runs after LSTM)
    float* PRE = out + 64;              // 96*32*4*64 = 786432 floats
    float* HA  = PRE + 786432;          // 196608 floats
    float* HB  = HA + 196608;           // 196608 floats
    float* wsf = (float*)d_ws;
    float* XG  = wsf;                   // 16*2048
    float* XL  = wsf + 32768;           // 16*128
    float* HP  = wsf + 34816;           // 3*16*16*64

    lstm_pre_kernel<<<96, 1024, 0, stream>>>(x, 12288, 128, Wih, bih, bhh, PRE);
    lstm_rec_kernel<<<1, 512, 0, stream>>>(Whh, PRE, HA, nullptr);
    lstm_pre_kernel<<<96, 1024, 0, stream>>>(HA, 128, 2048, Wih + 65536, bih + 512, bhh + 512, PRE);
    lstm_rec_kernel<<<1, 512, 0, stream>>>(Whh + 65536, PRE, HB, nullptr);
    lstm_pre_kernel<<<96, 1024, 0, stream>>>(HB, 128, 2048, Wih + 131072, bih + 1024, bhh + 1024, PRE);
    lstm_rec_kernel<<<1, 512, 0, stream>>>(Whh + 131072, PRE, HA, XL);

    gat_kernel<<<1536, 256, 0, stream>>>(x, adj, W_emb, b_emb, W1, a1, W2, a2, out + 64, XG);

    head_partial_kernel<<<48, 256, 0, stream>>>(XL, XG, hW1, HP);
    head_final_kernel<<<1, 256, 0, stream>>>(HP, hb1, hW2, hb2, W3d, b3d, W3r, b3r, W3v, b3v, out);
}

// Round 2
// 632.801 us; speedup vs baseline: 1.3507x; 1.3507x over previous
//
#include <hip/hip_runtime.h>
#include <hip/hip_bf16.h>

// ---------------------------------------------------------------------------
// HybridGATLSTM on MI355X — round 2.
//   lstm_pre   : layer-1 input projection (96 parallel blocks) + flag init
//   lstm_pipe  : 5 co-resident blocks pipelining R1 -> P2 -> R2 -> P3 -> R3
//                via device-scope flag handoff (release/acquire pattern)
//   gat        : unchanged from round 1
//   head_*     : unchanged from round 1
// LSTM scratch + flags live in the attn2 region of d_out (GAT runs after).
// ---------------------------------------------------------------------------

typedef _Float16 half8 __attribute__((ext_vector_type(8)));
typedef float floatx4 __attribute__((ext_vector_type(4)));
typedef float float4v __attribute__((ext_vector_type(4)));

#define LOG2E 1.44269504088896f

__device__ __forceinline__ float fast_exp(float x) {
    return __builtin_amdgcn_exp2f(x * LOG2E);
}
__device__ __forceinline__ float sigm(float x) {
    x = fminf(fmaxf(x, -30.f), 30.f);
    return __builtin_amdgcn_rcpf(1.f + __builtin_amdgcn_exp2f(-x * LOG2E));
}
__device__ __forceinline__ float tanhp(float x) {
    x = fminf(fmaxf(x, -15.f), 15.f);
    float e = __builtin_amdgcn_exp2f(-2.f * LOG2E * x);
    return (1.f - e) * __builtin_amdgcn_rcpf(1.f + e);
}
__device__ __forceinline__ void cvt_split(float v, _Float16& hi, _Float16& lo) {
    hi = (_Float16)v;
    lo = (_Float16)(v - (float)hi);
}
__device__ __forceinline__ void split8v(float4v v0, float4v v1, half8& hi, half8& lo) {
#pragma unroll
    for (int j = 0; j < 4; ++j) {
        _Float16 h = (_Float16)v0[j];
        hi[j] = h; lo[j] = (_Float16)(v0[j] - (float)h);
    }
#pragma unroll
    for (int j = 0; j < 4; ++j) {
        _Float16 h = (_Float16)v1[j];
        hi[4 + j] = h; lo[4 + j] = (_Float16)(v1[j] - (float)h);
    }
}

// Gate-row mapping: wave w (0..7), tile tt (0..3), lane sub (0..15):
//   row = tt*128 + 16*w + sub  -> tt0=i, tt1=f, tt2=g, tt3=o of hu = 16w+sub.
// One lane owns all 4 gates of one hidden unit => no cross-lane shuffles.
// Pre / gate matrices stored in MFMA D layout: [((t*32 + 4w+tt)*4 + reg)*64 + lane]

__device__ __forceinline__ void flag_wait(const int* flag, int need) {
    while (__hip_atomic_load(flag, __ATOMIC_ACQUIRE, __HIP_MEMORY_SCOPE_AGENT) < need)
        __builtin_amdgcn_s_sleep(1);
}
__device__ __forceinline__ void flag_set(int* flag, int val) {
    __threadfence();
    __hip_atomic_store(flag, val, __ATOMIC_RELEASE, __HIP_MEMORY_SCOPE_AGENT);
}

// ---------------------------------------------------------------------------
// Input-projection block (P role): Pre[t] = h_in[t](16x128) @ Wih^T + bias,
// streamed per step behind the producer's flag.
// ---------------------------------------------------------------------------
__device__ void proj_block(const float* __restrict__ Wih,
                           const float* __restrict__ bi, const float* __restrict__ bh,
                           const float* __restrict__ hin,   // [96][16][128]
                           float* __restrict__ PreOut,
                           const int* flag_in, int* flag_out)
{
    int tid = threadIdx.x;
    int w = tid >> 6, lane = tid & 63, quad = lane >> 4, sub = lane & 15;

    half8 bhi[4][4], blo[4][4];
    float bias[4];
#pragma unroll
    for (int tt = 0; tt < 4; ++tt) {
        int r = tt * 128 + 16 * w + sub;
        bias[tt] = bi[r] + bh[r];
#pragma unroll
        for (int kc = 0; kc < 4; ++kc) {
            const float4v* p = (const float4v*)(Wih + r * 128 + kc * 32 + quad * 8);
            split8v(p[0], p[1], bhi[tt][kc], blo[tt][kc]);
        }
    }

    for (int t = 0; t < 96; ++t) {
        if (tid == 0) flag_wait(flag_in, t + 1);
        __syncthreads();                    // acquire visible; prev stores drained
        if (tid == 0) flag_set(flag_out, t); // publish steps 0..t-1

        half8 ahi[4], alo[4];
        const float* hb = hin + t * 2048 + sub * 128;
#pragma unroll
        for (int kc = 0; kc < 4; ++kc) {
            const float4v* p = (const float4v*)(hb + kc * 32 + quad * 8);
            split8v(p[0], p[1], ahi[kc], alo[kc]);
        }
        floatx4 acc[4];
#pragma unroll
        for (int tt = 0; tt < 4; ++tt) {
            floatx4 a = {bias[tt], bias[tt], bias[tt], bias[tt]};
            acc[tt] = a;
        }
#pragma unroll
        for (int tt = 0; tt < 4; ++tt)
#pragma unroll
            for (int kc = 0; kc < 4; ++kc) {
                acc[tt] = __builtin_amdgcn_mfma_f32_16x16x32_f16(ahi[kc], bhi[tt][kc], acc[tt], 0, 0, 0);
                acc[tt] = __builtin_amdgcn_mfma_f32_16x16x32_f16(ahi[kc], blo[tt][kc], acc[tt], 0, 0, 0);
                acc[tt] = __builtin_amdgcn_mfma_f32_16x16x32_f16(alo[kc], bhi[tt][kc], acc[tt], 0, 0, 0);
            }
#pragma unroll
        for (int tt = 0; tt < 4; ++tt)
#pragma unroll
            for (int reg = 0; reg < 4; ++reg)
                PreOut[((t * 32 + 4 * w + tt) * 4 + reg) * 64 + lane] = acc[tt][reg];
    }
    __syncthreads();
    if (tid == 0) flag_set(flag_out, 96);
}

// ---------------------------------------------------------------------------
// Recurrence block (R role): gates = Pre[t] + h_{t-1} @ Whh^T; Whh resident in
// VGPRs (split fp16, 3 products). h double-buffered in LDS -> 1 barrier/step.
// ---------------------------------------------------------------------------
__device__ void rec_block(const float* __restrict__ Whh,
                          const float* __restrict__ Pre,
                          float* __restrict__ hseq,    // [96][16][128] or null
                          float* __restrict__ xl_out,  // [16][128] or null
                          const int* flag_in, int* flag_out)
{
    __shared__ _Float16 hbuf[2][2][2048];   // [buf][hi/lo][b*128 + swizzled hu]
    int tid = threadIdx.x;
    int w = tid >> 6, lane = tid & 63, quad = lane >> 4, sub = lane & 15;

    half8 whi[4][4], wlo[4][4];
#pragma unroll
    for (int tt = 0; tt < 4; ++tt) {
        int r = tt * 128 + 16 * w + sub;
#pragma unroll
        for (int kc = 0; kc < 4; ++kc) {
            const float4v* p = (const float4v*)(Whh + r * 128 + kc * 32 + quad * 8);
            split8v(p[0], p[1], whi[tt][kc], wlo[tt][kc]);
        }
    }
    for (int i = tid; i < 2048; i += 512) {
        hbuf[0][0][i] = (_Float16)0.f;
        hbuf[0][1][i] = (_Float16)0.f;
    }
    float cst[4] = {0.f, 0.f, 0.f, 0.f};
    int hu = 16 * w + sub;
    int grp = hu >> 3;

    for (int t = 0; t < 96; ++t) {
        if (flag_in && tid == 0) flag_wait(flag_in, t + 1);
        __syncthreads();   // h_{t-1} LDS writes drained + acquire visible
        if (flag_out && tid == 0) flag_set(flag_out, t);  // publish h[0..t-1]

        // Pre loads issued early, consumed after MFMAs (latency hidden)
        float cur[16];
#pragma unroll
        for (int tt = 0; tt < 4; ++tt)
#pragma unroll
            for (int reg = 0; reg < 4; ++reg)
                cur[tt * 4 + reg] = Pre[((t * 32 + 4 * w + tt) * 4 + reg) * 64 + lane];

        int rb = t & 1, wb = rb ^ 1;
        const half8* Hhi = (const half8*)hbuf[rb][0];
        const half8* Hlo = (const half8*)hbuf[rb][1];
        half8 ahi[4], alo[4];
#pragma unroll
        for (int kc = 0; kc < 4; ++kc) {
            int g = ((kc * 4 + quad) ^ sub) & 15;
            ahi[kc] = Hhi[sub * 16 + g];
            alo[kc] = Hlo[sub * 16 + g];
        }
        floatx4 acc[4];
#pragma unroll
        for (int tt = 0; tt < 4; ++tt) {
            floatx4 z = {0.f, 0.f, 0.f, 0.f};
            acc[tt] = z;
        }
#pragma unroll
        for (int tt = 0; tt < 4; ++tt)
#pragma unroll
            for (int kc = 0; kc < 4; ++kc) {
                acc[tt] = __builtin_amdgcn_mfma_f32_16x16x32_f16(ahi[kc], whi[tt][kc], acc[tt], 0, 0, 0);
                acc[tt] = __builtin_amdgcn_mfma_f32_16x16x32_f16(ahi[kc], wlo[tt][kc], acc[tt], 0, 0, 0);
                acc[tt] = __builtin_amdgcn_mfma_f32_16x16x32_f16(alo[kc], whi[tt][kc], acc[tt], 0, 0, 0);
            }
        // activations: this lane owns all 4 gates of hu for 4 batches
#pragma unroll
        for (int reg = 0; reg < 4; ++reg) {
            float gi = acc[0][reg] + cur[reg];
            float gf = acc[1][reg] + cur[4 + reg];
            float gg = acc[2][reg] + cur[8 + reg];
            float go = acc[3][reg] + cur[12 + reg];
            float c = sigm(gf) * cst[reg] + sigm(gi) * tanhp(gg);
            cst[reg] = c;
            float h = sigm(go) * tanhp(c);
            int b = quad * 4 + reg;
            _Float16 hh, hl; cvt_split(h, hh, hl);
            int lidx = b * 128 + (((grp ^ b) & 15) << 3) + (hu & 7);
            hbuf[wb][0][lidx] = hh;
            hbuf[wb][1][lidx] = hl;
            if (hseq) hseq[t * 2048 + b * 128 + hu] = h;
            if (xl_out && t == 95) xl_out[b * 128 + hu] = h;
        }
    }
    if (flag_out) {
        __syncthreads();
        if (tid == 0) flag_set(flag_out, 96);
    }
}

__global__ __launch_bounds__(512, 2) void lstm_pipe_kernel(
    const float* __restrict__ Whh, const float* __restrict__ Wih,
    const float* __restrict__ bih, const float* __restrict__ bhh,
    float* __restrict__ Pre1, float* __restrict__ Pre2, float* __restrict__ Pre3,
    float* __restrict__ h1, float* __restrict__ h2, float* __restrict__ xl,
    int* flags)
{
    int role = blockIdx.x;
    if (role == 0)      rec_block(Whh,          Pre1, h1, nullptr, nullptr,  flags + 0);
    else if (role == 1) proj_block(Wih + 65536,  bih + 512,  bhh + 512,  h1, Pre2, flags + 0, flags + 1);
    else if (role == 2) rec_block(Whh + 65536,  Pre2, h2, nullptr, flags + 1, flags + 2);
    else if (role == 3) proj_block(Wih + 131072, bih + 1024, bhh + 1024, h2, Pre3, flags + 2, flags + 3);
    else                rec_block(Whh + 131072, Pre3, nullptr, xl, flags + 3, nullptr);
}

// ---------------------------------------------------------------------------
// Layer-1 input projection: one block per timestep; also zeroes the flags.
// ---------------------------------------------------------------------------
__global__ __launch_bounds__(512) void lstm_pre_kernel(
    const float* __restrict__ x,      // [16][96][128]
    const float* __restrict__ Wih,
    const float* __restrict__ bih, const float* __restrict__ bhh,
    float* __restrict__ Pre, int* flags)
{
    int t = blockIdx.x;
    int tid = threadIdx.x;
    if (t == 0 && tid < 16) flags[tid] = 0;
    int w = tid >> 6, lane = tid & 63, quad = lane >> 4, sub = lane & 15;

    half8 ahi[4], alo[4];
    const float* arow = x + sub * 12288 + t * 128;
#pragma unroll
    for (int kc = 0; kc < 4; ++kc) {
        const float4v* p = (const float4v*)(arow + kc * 32 + quad * 8);
        split8v(p[0], p[1], ahi[kc], alo[kc]);
    }
#pragma unroll
    for (int tt = 0; tt < 4; ++tt) {
        int r = tt * 128 + 16 * w + sub;
        half8 bhi[4], blo[4];
#pragma unroll
        for (int kc = 0; kc < 4; ++kc) {
            const float4v* p = (const float4v*)(Wih + r * 128 + kc * 32 + quad * 8);
            split8v(p[0], p[1], bhi[kc], blo[kc]);
        }
        float bias = bih[r] + bhh[r];
        floatx4 acc = {bias, bias, bias, bias};
#pragma unroll
        for (int kc = 0; kc < 4; ++kc) {
            acc = __builtin_amdgcn_mfma_f32_16x16x32_f16(ahi[kc], bhi[kc], acc, 0, 0, 0);
            acc = __builtin_amdgcn_mfma_f32_16x16x32_f16(ahi[kc], blo[kc], acc, 0, 0, 0);
            acc = __builtin_amdgcn_mfma_f32_16x16x32_f16(alo[kc], bhi[kc], acc, 0, 0, 0);
        }
#pragma unroll
        for (int reg = 0; reg < 4; ++reg)
            Pre[((t * 32 + 4 * w + tt) * 4 + reg) * 64 + lane] = acc[reg];
    }
}

// ---------------------------------------------------------------------------
// GAT (unchanged from round 1)
// ---------------------------------------------------------------------------
__global__ __launch_bounds__(256) void gat_kernel(
    const float* __restrict__ x, const float* __restrict__ adj,
    const float* __restrict__ W_emb, const float* __restrict__ b_emb,
    const float* __restrict__ W1, const float* __restrict__ a1,
    const float* __restrict__ W2, const float* __restrict__ a2,
    float* __restrict__ attn_out, float* __restrict__ xg)
{
    int m = blockIdx.x;
    int tid = threadIdx.x;
    __shared__ float xv[128];
    __shared__ unsigned char adjb[128 * 132];
    __shared__ float u1[32], v1[32];
    __shared__ float coef[4];
    __shared__ float s1v[128];
    __shared__ float h2s[128 * 33];
    __shared__ float wh2[128 * 17];
    __shared__ float Lv[128], Rv[128], mx2[128], rd2[128];
    __shared__ float m_h[2][128], d_h[2][128], s_h[2][128];

    if (tid < 128) xv[tid] = x[m * 128 + tid];
    for (int idx = tid; idx < 16384; idx += 256) {
        int i = idx >> 7, j = idx & 127;
        adjb[i * 132 + j] = adj[idx] > 0.f ? 1 : 0;
    }
    if (tid < 32) {
        float su = 0.f, sv = 0.f;
        for (int kk = 0; kk < 32; ++kk) {
            su += W_emb[kk] * W1[kk * 32 + tid];
            sv += b_emb[kk] * W1[kk * 32 + tid];
        }
        u1[tid] = su; v1[tid] = sv;
    }
    __syncthreads();
    if (tid < 4) {
        const float* av = a1 + ((tid >= 2) ? 32 : 0);
        const float* uv = (tid & 1) ? v1 : u1;
        float s = 0.f;
        for (int f = 0; f < 32; ++f) s += uv[f] * av[f];
        coef[tid] = s;
    }
    __syncthreads();
    float cL = coef[0], dL = coef[1], cR = coef[2], dR = coef[3];

    {
        int i = tid & 127, hf = tid >> 7;
        float Li = xv[i] * cL + dL;
        int j0 = hf * 64;
        float mmax = -3.0e38f;
        for (int j = j0; j < j0 + 64; ++j) {
            if (adjb[i * 132 + j]) {
                float e = Li + xv[j] * cR + dR;
                e = e > 0.f ? e : 0.2f * e;
                mmax = fmaxf(mmax, e);
            }
        }
        float den = 0.f, wsum = 0.f;
        for (int j = j0; j < j0 + 64; ++j) {
            if (adjb[i * 132 + j]) {
                float e = Li + xv[j] * cR + dR;
                e = e > 0.f ? e : 0.2f * e;
                float p = fast_exp(e - mmax);
                den += p; wsum += p * xv[j];
            }
        }
        m_h[hf][i] = mmax; d_h[hf][i] = den; s_h[hf][i] = wsum;
    }
    __syncthreads();
    if (tid < 128) {
        int i = tid;
        float m0 = m_h[0][i], m1 = m_h[1][i];
        float mm = fmaxf(m0, m1);
        float sc0 = fast_exp(m0 - mm), sc1 = fast_exp(m1 - mm);
        float den = d_h[0][i] * sc0 + d_h[1][i] * sc1;
        float wsum = s_h[0][i] * sc0 + s_h[1][i] * sc1;
        s1v[i] = wsum / den;
    }
    __syncthreads();
    for (int e = tid; e < 4096; e += 256) {
        int i = e >> 5, f = e & 31;
        float v = s1v[i] * u1[f] + v1[f];
        h2s[i * 33 + f] = v > 0.f ? v : fast_exp(v) - 1.f;
    }
    __syncthreads();
    {
        int i = tid >> 1, g0 = (tid & 1) * 8;
        float accv[8] = {0.f, 0.f, 0.f, 0.f, 0.f, 0.f, 0.f, 0.f};
        for (int f = 0; f < 32; ++f) {
            float hv = h2s[i * 33 + f];
#pragma unroll
            for (int g = 0; g < 8; ++g) accv[g] += hv * W2[f * 16 + g0 + g];
        }
#pragma unroll
        for (int g = 0; g < 8; ++g) wh2[i * 17 + g0 + g] = accv[g];
    }
    __syncthreads();
    {
        int i = tid & 127, which = tid >> 7;
        const float* aa = a2 + which * 16;
        float s = 0.f;
        for (int g = 0; g < 16; ++g) s += wh2[i * 17 + g] * aa[g];
        (which ? Rv : Lv)[i] = s;
    }
    __syncthreads();
    {
        int i = tid & 127, hf = tid >> 7;
        float Li = Lv[i];
        int j0 = hf * 64;
        float mmax = -3.0e38f;
        for (int j = j0; j < j0 + 64; ++j) {
            if (adjb[i * 132 + j]) {
                float e = Li + Rv[j];
                e = e > 0.f ? e : 0.2f * e;
                mmax = fmaxf(mmax, e);
            }
        }
        float den = 0.f;
        for (int j = j0; j < j0 + 64; ++j) {
            if (adjb[i * 132 + j]) {
                float e = Li + Rv[j];
                e = e > 0.f ? e : 0.2f * e;
                den += fast_exp(e - mmax);
            }
        }
        m_h[hf][i] = mmax; d_h[hf][i] = den;
    }
    __syncthreads();
    if (tid < 128) {
        int i = tid;
        float m0 = m_h[0][i], m1 = m_h[1][i];
        float mm = fmaxf(m0, m1);
        float den = d_h[0][i] * fast_exp(m0 - mm) + d_h[1][i] * fast_exp(m1 - mm);
        mx2[i] = mm; rd2[i] = 1.0f / den;
    }
    __syncthreads();
    float* aout = attn_out + m * 16384;
    for (int idx = tid; idx < 16384; idx += 256) {
        int i = idx >> 7, j = idx & 127;
        float p = 0.f;
        if (adjb[i * 132 + j]) {
            float e = Lv[i] + Rv[j];
            e = e > 0.f ? e : 0.2f * e;
            p = fast_exp(e - mx2[i]) * rd2[i];
        }
        aout[idx] = p;
    }
    if (m % 96 == 95) {
        int b = m / 96;
        int i = tid >> 1, g0 = (tid & 1) * 8;
        float accv[8] = {0.f, 0.f, 0.f, 0.f, 0.f, 0.f, 0.f, 0.f};
        for (int j = 0; j < 128; ++j) {
            float p = 0.f;
            if (adjb[i * 132 + j]) {
                float e = Lv[i] + Rv[j];
                e = e > 0.f ? e : 0.2f * e;
                p = fast_exp(e - mx2[i]) * rd2[i];
            }
#pragma unroll
            for (int g = 0; g < 8; ++g) accv[g] += p * wh2[j * 17 + g0 + g];
        }
#pragma unroll
        for (int g = 0; g < 8; ++g) xg[b * 2048 + i * 16 + g0 + g] = accv[g];
    }
}

// ---------------------------------------------------------------------------
// Heads (unchanged from round 1)
// ---------------------------------------------------------------------------
__global__ __launch_bounds__(256) void head_partial_kernel(
    const float* __restrict__ xl, const float* __restrict__ xg,
    const float* __restrict__ W1, float* __restrict__ hp)
{
    int k = blockIdx.x >> 4, chunk = blockIdx.x & 15;
    int d = threadIdx.x & 63, bg = threadIdx.x >> 6;
    float acc[4] = {0.f, 0.f, 0.f, 0.f};
    int c0 = chunk * 136;
    for (int cc = c0; cc < c0 + 136; ++cc) {
        float wv = W1[(k * 2176 + cc) * 64 + d];
#pragma unroll
        for (int u = 0; u < 4; ++u) {
            int b = bg * 4 + u;
            float cv = (cc < 128) ? xl[b * 128 + cc] : xg[b * 2048 + cc - 128];
            acc[u] += wv * cv;
        }
    }
#pragma unroll
    for (int u = 0; u < 4; ++u)
        hp[(((k * 16 + chunk) * 16) + bg * 4 + u) * 64 + d] = acc[u];
}

__global__ __launch_bounds__(256) void head_final_kernel(
    const float* __restrict__ hp, const float* __restrict__ b1,
    const float* __restrict__ W2, const float* __restrict__ b2,
    const float* __restrict__ W3d, const float* __restrict__ b3d,
    const float* __restrict__ W3r, const float* __restrict__ b3r,
    const float* __restrict__ W3v, const float* __restrict__ b3v,
    float* __restrict__ out)
{
    __shared__ float h1s[3 * 16 * 64];
    __shared__ float h2s[3 * 16 * 32];
    int tid = threadIdx.x;
    for (int o = tid; o < 3072; o += 256) {
        int k = o >> 10, rem = o & 1023, b = rem >> 6, d = rem & 63;
        float s = b1[k * 64 + d];
        for (int ch = 0; ch < 16; ++ch)
            s += hp[(((k * 16 + ch) * 16) + b) * 64 + d];
        h1s[o] = fmaxf(s, 0.f);
    }
    __syncthreads();
    for (int o = tid; o < 1536; o += 256) {
        int k = o >> 9, rem = o & 511, b = rem >> 5, e = rem & 31;
        float s = b2[k * 32 + e];
        for (int dd = 0; dd < 64; ++dd)
            s += h1s[(k * 16 + b) * 64 + dd] * W2[(k * 64 + dd) * 32 + e];
        h2s[o] = fmaxf(s, 0.f);
    }
    __syncthreads();
    if (tid < 64) {
        if (tid < 16) {
            int b = tid; float s = b3d[0];
            for (int e = 0; e < 32; ++e) s += h2s[b * 32 + e] * W3d[e];
            out[b] = s;
        } else if (tid < 32) {
            int b = tid - 16; float s = b3r[0];
            for (int e = 0; e < 32; ++e) s += h2s[(16 + b) * 32 + e] * W3r[e];
            out[16 + b] = s;
        } else {
            int b = (tid - 32) >> 1, j = tid & 1; float s = b3v[j];
            for (int e = 0; e < 32; ++e) s += h2s[(32 + b) * 32 + e] * W3v[e * 2 + j];
            out[32 + b * 2 + j] = s;
        }
    }
}

// ---------------------------------------------------------------------------
extern "C" void kernel_launch(void* const* d_in, const int* in_sizes, int n_in,
                              void* d_out, int out_size, void* d_ws, size_t ws_size,
                              hipStream_t stream)
{
    const float* x     = (const float*)d_in[0];
    const float* adj   = (const float*)d_in[1];
    const float* W_emb = (const float*)d_in[2];
    const float* b_emb = (const float*)d_in[3];
    const float* W1    = (const float*)d_in[4];
    const float* a1    = (const float*)d_in[5];
    const float* W2    = (const float*)d_in[6];
    const float* a2    = (const float*)d_in[7];
    const float* Wih   = (const float*)d_in[8];
    const float* Whh   = (const float*)d_in[9];
    const float* bih   = (const float*)d_in[10];
    const float* bhh   = (const float*)d_in[11];
    const float* hW1   = (const float*)d_in[12];
    const float* hb1   = (const float*)d_in[13];
    const float* hW2   = (const float*)d_in[14];
    const float* hb2   = (const float*)d_in[15];
    const float* W3d   = (const float*)d_in[16];
    const float* b3d   = (const float*)d_in[17];
    const float* W3r   = (const float*)d_in[18];
    const float* b3r   = (const float*)d_in[19];
    const float* W3v   = (const float*)d_in[20];
    const float* b3v   = (const float*)d_in[21];

    float* out = (float*)d_out;
    // scratch inside the attn2 region of d_out (GAT overwrites it afterwards)
    float* S    = out + 64;
    float* Pre1 = S;                    // 786432
    float* Pre2 = S + 786432;           // 786432
    float* Pre3 = S + 1572864;          // 786432
    float* H1   = S + 2359296;          // 196608
    float* H2   = S + 2555904;          // 196608
    int*   FLG  = (int*)(S + 2752512);  // 16 ints

    float* wsf = (float*)d_ws;
    float* XG  = wsf;                   // 16*2048
    float* XL  = wsf + 32768;           // 16*128
    float* HP  = wsf + 34816;           // 3*16*16*64

    lstm_pre_kernel<<<96, 512, 0, stream>>>(x, Wih, bih, bhh, Pre1, FLG);
    lstm_pipe_kernel<<<5, 512, 0, stream>>>(Whh, Wih, bih, bhh,
                                            Pre1, Pre2, Pre3, H1, H2, XL, FLG);
    gat_kernel<<<1536, 256, 0, stream>>>(x, adj, W_emb, b_emb, W1, a1, W2, a2, out + 64, XG);
    head_partial_kernel<<<48, 256, 0, stream>>>(XL, XG, hW1, HP);
    head_final_kernel<<<1, 256, 0, stream>>>(HP, hb1, hW2, hb2, W3d, b3d, W3r, b3r, W3v, b3v, out);
}

// Round 3
// 632.538 us; speedup vs baseline: 1.3513x; 1.0004x over previous
//
#include <hip/hip_runtime.h>
#include <hip/hip_bf16.h>

// ---------------------------------------------------------------------------
// HybridGATLSTM on MI355X — round 3.
//   lstm_batch : 16 blocks, one per batch element; all 3 LSTM layers run
//                inside the block (proj = M=96 MFMA GEMM, recurrence = M=1
//                MFMA GEMV with h broadcast via LDS). No inter-block sync.
//   gat        : unchanged
//   head_*     : unchanged
// Per-block Pre scratch lives in the attn2 region of d_out (GAT runs after).
// ---------------------------------------------------------------------------

typedef _Float16 half8 __attribute__((ext_vector_type(8)));
typedef float floatx4 __attribute__((ext_vector_type(4)));
typedef float float4v __attribute__((ext_vector_type(4)));

#define LOG2E 1.44269504088896f

__device__ __forceinline__ float fast_exp(float x) {
    return __builtin_amdgcn_exp2f(x * LOG2E);
}
__device__ __forceinline__ float sigm(float x) {
    x = fminf(fmaxf(x, -30.f), 30.f);
    return __builtin_amdgcn_rcpf(1.f + __builtin_amdgcn_exp2f(-x * LOG2E));
}
__device__ __forceinline__ float tanhp(float x) {
    x = fminf(fmaxf(x, -15.f), 15.f);
    float e = __builtin_amdgcn_exp2f(-2.f * LOG2E * x);
    return (1.f - e) * __builtin_amdgcn_rcpf(1.f + e);
}
__device__ __forceinline__ void cvt_split(float v, _Float16& hi, _Float16& lo) {
    hi = (_Float16)v;
    lo = (_Float16)(v - (float)hi);
}
__device__ __forceinline__ void split8v(float4v v0, float4v v1, half8& hi, half8& lo) {
#pragma unroll
    for (int j = 0; j < 4; ++j) {
        _Float16 h = (_Float16)v0[j];
        hi[j] = h; lo[j] = (_Float16)(v0[j] - (float)h);
    }
#pragma unroll
    for (int j = 0; j < 4; ++j) {
        _Float16 h = (_Float16)v1[j];
        hi[4 + j] = h; lo[4 + j] = (_Float16)(v1[j] - (float)h);
    }
}

// Gate-row mapping: wave w (0..7), tile tt (0..3), lane sub (0..15):
//   row r = tt*128 + 16*w + sub   (tt: 0=i, 1=f, 2=g, 3=o; hu = 16w+sub)
// MFMA D layout: col(lane&15)=n(B-row index), row(quad*4+reg)=m(A-row index).

// ---------------------------------------------------------------------------
// One block per batch element. Layers sequential; no cross-block traffic.
// ---------------------------------------------------------------------------
__global__ __launch_bounds__(512, 2) void lstm_batch_kernel(
    const float* __restrict__ x,     // [16][96][128]
    const float* __restrict__ Wih,   // [3][512][128]
    const float* __restrict__ Whh,   // [3][512][128]
    const float* __restrict__ bih,   // [3][512]
    const float* __restrict__ bhh,   // [3][512]
    float* __restrict__ scratch,     // per block: 3 * 96*512 floats (Pre)
    float* __restrict__ xl_out)      // [16][128]
{
    int b = blockIdx.x;
    float* PreBase = scratch + b * (3 * 96 * 512);

    int tid = threadIdx.x;
    int w = tid >> 6, lane = tid & 63, quad = lane >> 4, sub = lane & 15;

    __shared__ alignas(16) _Float16 hstate[2][2][128];  // [buf][hi/lo][hu]
    __shared__ float Hseq[96 * 132];                    // padded rows (+4)

    half8 whi[4][4], wlo[4][4];
    float bias[4];

    for (int layer = 0; layer < 3; ++layer) {
        const float* WihL = Wih + layer * 65536;
        const float* WhhL = Whh + layer * 65536;
        float* Pre = PreBase + layer * (96 * 512);

        // ---- input-projection weights (Wih) as split-fp16 fragments
#pragma unroll
        for (int tt = 0; tt < 4; ++tt) {
            int r = tt * 128 + 16 * w + sub;
            bias[tt] = bih[layer * 512 + r] + bhh[layer * 512 + r];
#pragma unroll
            for (int kc = 0; kc < 4; ++kc) {
                const float4v* p = (const float4v*)(WihL + r * 128 + kc * 32 + quad * 8);
                split8v(p[0], p[1], whi[tt][kc], wlo[tt][kc]);
            }
        }

        // ---- proj GEMM: Pre[t][r] = A[t] . Wih[r] + bias, t = 0..95 (M=96)
        for (int mt = 0; mt < 6; ++mt) {
            half8 ahi[4], alo[4];
            if (layer == 0) {
                const float* arow = x + b * 12288 + (mt * 16 + sub) * 128;
#pragma unroll
                for (int kc = 0; kc < 4; ++kc) {
                    const float4v* p = (const float4v*)(arow + kc * 32 + quad * 8);
                    split8v(p[0], p[1], ahi[kc], alo[kc]);
                }
            } else {
                const float* arow = Hseq + (mt * 16 + sub) * 132;
#pragma unroll
                for (int kc = 0; kc < 4; ++kc) {
                    const float4v* p = (const float4v*)(arow + kc * 32 + quad * 8);
                    split8v(p[0], p[1], ahi[kc], alo[kc]);
                }
            }
            floatx4 acc[4];
#pragma unroll
            for (int tt = 0; tt < 4; ++tt) {
                floatx4 a = {bias[tt], bias[tt], bias[tt], bias[tt]};
                acc[tt] = a;
            }
#pragma unroll
            for (int tt = 0; tt < 4; ++tt)
#pragma unroll
                for (int kc = 0; kc < 4; ++kc) {
                    acc[tt] = __builtin_amdgcn_mfma_f32_16x16x32_f16(ahi[kc], whi[tt][kc], acc[tt], 0, 0, 0);
                    acc[tt] = __builtin_amdgcn_mfma_f32_16x16x32_f16(ahi[kc], wlo[tt][kc], acc[tt], 0, 0, 0);
                    acc[tt] = __builtin_amdgcn_mfma_f32_16x16x32_f16(alo[kc], whi[tt][kc], acc[tt], 0, 0, 0);
                }
            // store: m = mt*16 + quad*4 + reg (timestep), n = tt*128+16w+sub
#pragma unroll
            for (int tt = 0; tt < 4; ++tt)
#pragma unroll
                for (int reg = 0; reg < 4; ++reg)
                    Pre[(mt * 16 + quad * 4 + reg) * 512 + tt * 128 + 16 * w + sub] = acc[tt][reg];
        }

        // ---- recurrence weights (Whh) overwrite the fragment registers
#pragma unroll
        for (int tt = 0; tt < 4; ++tt) {
            int r = tt * 128 + 16 * w + sub;
#pragma unroll
            for (int kc = 0; kc < 4; ++kc) {
                const float4v* p = (const float4v*)(WhhL + r * 128 + kc * 32 + quad * 8);
                split8v(p[0], p[1], whi[tt][kc], wlo[tt][kc]);
            }
        }
        if (tid < 128) {
            hstate[0][0][tid] = (_Float16)0.f;
            hstate[0][1][tid] = (_Float16)0.f;
        }
        __syncthreads();   // Pre stores drained; h zeroed; Hseq reads done

        // ---- recurrence: 96 steps, M=1 GEMV via MFMA, h broadcast from LDS
        float cvar = 0.f;
        int hu = 16 * w + sub;
        for (int t = 0; t < 96; ++t) {
            int rb = t & 1, wb = rb ^ 1;
            float cur[4];
            if (quad == 0) {
#pragma unroll
                for (int tt = 0; tt < 4; ++tt)
                    cur[tt] = Pre[t * 512 + tt * 128 + hu];
            }
            half8 ahi[4], alo[4];
#pragma unroll
            for (int kc = 0; kc < 4; ++kc) {
                ahi[kc] = *(const half8*)&hstate[rb][0][kc * 32 + quad * 8];
                alo[kc] = *(const half8*)&hstate[rb][1][kc * 32 + quad * 8];
            }
            floatx4 acc[4];
#pragma unroll
            for (int tt = 0; tt < 4; ++tt) {
                floatx4 z = {0.f, 0.f, 0.f, 0.f};
                acc[tt] = z;
            }
#pragma unroll
            for (int tt = 0; tt < 4; ++tt)
#pragma unroll
                for (int kc = 0; kc < 4; ++kc) {
                    acc[tt] = __builtin_amdgcn_mfma_f32_16x16x32_f16(ahi[kc], whi[tt][kc], acc[tt], 0, 0, 0);
                    acc[tt] = __builtin_amdgcn_mfma_f32_16x16x32_f16(ahi[kc], wlo[tt][kc], acc[tt], 0, 0, 0);
                    acc[tt] = __builtin_amdgcn_mfma_f32_16x16x32_f16(alo[kc], whi[tt][kc], acc[tt], 0, 0, 0);
                }
            if (quad == 0) {   // D row m=0 lives in reg 0 of quad-0 lanes
                float gi = acc[0][0] + cur[0];
                float gf = acc[1][0] + cur[1];
                float gg = acc[2][0] + cur[2];
                float go = acc[3][0] + cur[3];
                float c = sigm(gf) * cvar + sigm(gi) * tanhp(gg);
                cvar = c;
                float h = sigm(go) * tanhp(c);
                _Float16 hh, hl; cvt_split(h, hh, hl);
                hstate[wb][0][hu] = hh;
                hstate[wb][1][hu] = hl;
                if (layer < 2) Hseq[t * 132 + hu] = h;
                else if (t == 95) xl_out[b * 128 + hu] = h;
            }
            __syncthreads();
        }
        __syncthreads();   // Hseq complete before next layer's proj reads
    }
}

// ---------------------------------------------------------------------------
// GAT (unchanged)
// ---------------------------------------------------------------------------
__global__ __launch_bounds__(256) void gat_kernel(
    const float* __restrict__ x, const float* __restrict__ adj,
    const float* __restrict__ W_emb, const float* __restrict__ b_emb,
    const float* __restrict__ W1, const float* __restrict__ a1,
    const float* __restrict__ W2, const float* __restrict__ a2,
    float* __restrict__ attn_out, float* __restrict__ xg)
{
    int m = blockIdx.x;
    int tid = threadIdx.x;
    __shared__ float xv[128];
    __shared__ unsigned char adjb[128 * 132];
    __shared__ float u1[32], v1[32];
    __shared__ float coef[4];
    __shared__ float s1v[128];
    __shared__ float h2s[128 * 33];
    __shared__ float wh2[128 * 17];
    __shared__ float Lv[128], Rv[128], mx2[128], rd2[128];
    __shared__ float m_h[2][128], d_h[2][128], s_h[2][128];

    if (tid < 128) xv[tid] = x[m * 128 + tid];
    for (int idx = tid; idx < 16384; idx += 256) {
        int i = idx >> 7, j = idx & 127;
        adjb[i * 132 + j] = adj[idx] > 0.f ? 1 : 0;
    }
    if (tid < 32) {
        float su = 0.f, sv = 0.f;
        for (int kk = 0; kk < 32; ++kk) {
            su += W_emb[kk] * W1[kk * 32 + tid];
            sv += b_emb[kk] * W1[kk * 32 + tid];
        }
        u1[tid] = su; v1[tid] = sv;
    }
    __syncthreads();
    if (tid < 4) {
        const float* av = a1 + ((tid >= 2) ? 32 : 0);
        const float* uv = (tid & 1) ? v1 : u1;
        float s = 0.f;
        for (int f = 0; f < 32; ++f) s += uv[f] * av[f];
        coef[tid] = s;
    }
    __syncthreads();
    float cL = coef[0], dL = coef[1], cR = coef[2], dR = coef[3];

    {
        int i = tid & 127, hf = tid >> 7;
        float Li = xv[i] * cL + dL;
        int j0 = hf * 64;
        float mmax = -3.0e38f;
        for (int j = j0; j < j0 + 64; ++j) {
            if (adjb[i * 132 + j]) {
                float e = Li + xv[j] * cR + dR;
                e = e > 0.f ? e : 0.2f * e;
                mmax = fmaxf(mmax, e);
            }
        }
        float den = 0.f, wsum = 0.f;
        for (int j = j0; j < j0 + 64; ++j) {
            if (adjb[i * 132 + j]) {
                float e = Li + xv[j] * cR + dR;
                e = e > 0.f ? e : 0.2f * e;
                float p = fast_exp(e - mmax);
                den += p; wsum += p * xv[j];
            }
        }
        m_h[hf][i] = mmax; d_h[hf][i] = den; s_h[hf][i] = wsum;
    }
    __syncthreads();
    if (tid < 128) {
        int i = tid;
        float m0 = m_h[0][i], m1 = m_h[1][i];
        float mm = fmaxf(m0, m1);
        float sc0 = fast_exp(m0 - mm), sc1 = fast_exp(m1 - mm);
        float den = d_h[0][i] * sc0 + d_h[1][i] * sc1;
        float wsum = s_h[0][i] * sc0 + s_h[1][i] * sc1;
        s1v[i] = wsum / den;
    }
    __syncthreads();
    for (int e = tid; e < 4096; e += 256) {
        int i = e >> 5, f = e & 31;
        float v = s1v[i] * u1[f] + v1[f];
        h2s[i * 33 + f] = v > 0.f ? v : fast_exp(v) - 1.f;
    }
    __syncthreads();
    {
        int i = tid >> 1, g0 = (tid & 1) * 8;
        float accv[8] = {0.f, 0.f, 0.f, 0.f, 0.f, 0.f, 0.f, 0.f};
        for (int f = 0; f < 32; ++f) {
            float hv = h2s[i * 33 + f];
#pragma unroll
            for (int g = 0; g < 8; ++g) accv[g] += hv * W2[f * 16 + g0 + g];
        }
#pragma unroll
        for (int g = 0; g < 8; ++g) wh2[i * 17 + g0 + g] = accv[g];
    }
    __syncthreads();
    {
        int i = tid & 127, which = tid >> 7;
        const float* aa = a2 + which * 16;
        float s = 0.f;
        for (int g = 0; g < 16; ++g) s += wh2[i * 17 + g] * aa[g];
        (which ? Rv : Lv)[i] = s;
    }
    __syncthreads();
    {
        int i = tid & 127, hf = tid >> 7;
        float Li = Lv[i];
        int j0 = hf * 64;
        float mmax = -3.0e38f;
        for (int j = j0; j < j0 + 64; ++j) {
            if (adjb[i * 132 + j]) {
                float e = Li + Rv[j];
                e = e > 0.f ? e : 0.2f * e;
                mmax = fmaxf(mmax, e);
            }
        }
        float den = 0.f;
        for (int j = j0; j < j0 + 64; ++j) {
            if (adjb[i * 132 + j]) {
                float e = Li + Rv[j];
                e = e > 0.f ? e : 0.2f * e;
                den += fast_exp(e - mmax);
            }
        }
        m_h[hf][i] = mmax; d_h[hf][i] = den;
    }
    __syncthreads();
    if (tid < 128) {
        int i = tid;
        float m0 = m_h[0][i], m1 = m_h[1][i];
        float mm = fmaxf(m0, m1);
        float den = d_h[0][i] * fast_exp(m0 - mm) + d_h[1][i] * fast_exp(m1 - mm);
        mx2[i] = mm; rd2[i] = 1.0f / den;
    }
    __syncthreads();
    float* aout = attn_out + m * 16384;
    for (int idx = tid; idx < 16384; idx += 256) {
        int i = idx >> 7, j = idx & 127;
        float p = 0.f;
        if (adjb[i * 132 + j]) {
            float e = Lv[i] + Rv[j];
            e = e > 0.f ? e : 0.2f * e;
            p = fast_exp(e - mx2[i]) * rd2[i];
        }
        aout[idx] = p;
    }
    if (m % 96 == 95) {
        int b = m / 96;
        int i = tid >> 1, g0 = (tid & 1) * 8;
        float accv[8] = {0.f, 0.f, 0.f, 0.f, 0.f, 0.f, 0.f, 0.f};
        for (int j = 0; j < 128; ++j) {
            float p = 0.f;
            if (adjb[i * 132 + j]) {
                float e = Lv[i] + Rv[j];
                e = e > 0.f ? e : 0.2f * e;
                p = fast_exp(e - mx2[i]) * rd2[i];
            }
#pragma unroll
            for (int g = 0; g < 8; ++g) accv[g] += p * wh2[j * 17 + g0 + g];
        }
#pragma unroll
        for (int g = 0; g < 8; ++g) xg[b * 2048 + i * 16 + g0 + g] = accv[g];
    }
}

// ---------------------------------------------------------------------------
// Heads (unchanged)
// ---------------------------------------------------------------------------
__global__ __launch_bounds__(256) void head_partial_kernel(
    const float* __restrict__ xl, const float* __restrict__ xg,
    const float* __restrict__ W1, float* __restrict__ hp)
{
    int k = blockIdx.x >> 4, chunk = blockIdx.x & 15;
    int d = threadIdx.x & 63, bg = threadIdx.x >> 6;
    float acc[4] = {0.f, 0.f, 0.f, 0.f};
    int c0 = chunk * 136;
    for (int cc = c0; cc < c0 + 136; ++cc) {
        float wv = W1[(k * 2176 + cc) * 64 + d];
#pragma unroll
        for (int u = 0; u < 4; ++u) {
            int b = bg * 4 + u;
            float cv = (cc < 128) ? xl[b * 128 + cc] : xg[b * 2048 + cc - 128];
            acc[u] += wv * cv;
        }
    }
#pragma unroll
    for (int u = 0; u < 4; ++u)
        hp[(((k * 16 + chunk) * 16) + bg * 4 + u) * 64 + d] = acc[u];
}

__global__ __launch_bounds__(256) void head_final_kernel(
    const float* __restrict__ hp, const float* __restrict__ b1,
    const float* __restrict__ W2, const float* __restrict__ b2,
    const float* __restrict__ W3d, const float* __restrict__ b3d,
    const float* __restrict__ W3r, const float* __restrict__ b3r,
    const float* __restrict__ W3v, const float* __restrict__ b3v,
    float* __restrict__ out)
{
    __shared__ float h1s[3 * 16 * 64];
    __shared__ float h2s[3 * 16 * 32];
    int tid = threadIdx.x;
    for (int o = tid; o < 3072; o += 256) {
        int k = o >> 10, rem = o & 1023, b = rem >> 6, d = rem & 63;
        float s = b1[k * 64 + d];
        for (int ch = 0; ch < 16; ++ch)
            s += hp[(((k * 16 + ch) * 16) + b) * 64 + d];
        h1s[o] = fmaxf(s, 0.f);
    }
    __syncthreads();
    for (int o = tid; o < 1536; o += 256) {
        int k = o >> 9, rem = o & 511, b = rem >> 5, e = rem & 31;
        float s = b2[k * 32 + e];
        for (int dd = 0; dd < 64; ++dd)
            s += h1s[(k * 16 + b) * 64 + dd] * W2[(k * 64 + dd) * 32 + e];
        h2s[o] = fmaxf(s, 0.f);
    }
    __syncthreads();
    if (tid < 64) {
        if (tid < 16) {
            int b = tid; float s = b3d[0];
            for (int e = 0; e < 32; ++e) s += h2s[b * 32 + e] * W3d[e];
            out[b] = s;
        } else if (tid < 32) {
            int b = tid - 16; float s = b3r[0];
            for (int e = 0; e < 32; ++e) s += h2s[(16 + b) * 32 + e] * W3r[e];
            out[16 + b] = s;
        } else {
            int b = (tid - 32) >> 1, j = tid & 1; float s = b3v[j];
            for (int e = 0; e < 32; ++e) s += h2s[(32 + b) * 32 + e] * W3v[e * 2 + j];
            out[32 + b * 2 + j] = s;
        }
    }
}

// ---------------------------------------------------------------------------
extern "C" void kernel_launch(void* const* d_in, const int* in_sizes, int n_in,
                              void* d_out, int out_size, void* d_ws, size_t ws_size,
                              hipStream_t stream)
{
    const float* x     = (const float*)d_in[0];
    const float* adj   = (const float*)d_in[1];
    const float* W_emb = (const float*)d_in[2];
    const float* b_emb = (const float*)d_in[3];
    const float* W1    = (const float*)d_in[4];
    const float* a1    = (const float*)d_in[5];
    const float* W2    = (const float*)d_in[6];
    const float* a2    = (const float*)d_in[7];
    const float* Wih   = (const float*)d_in[8];
    const float* Whh   = (const float*)d_in[9];
    const float* bih   = (const float*)d_in[10];
    const float* bhh   = (const float*)d_in[11];
    const float* hW1   = (const float*)d_in[12];
    const float* hb1   = (const float*)d_in[13];
    const float* hW2   = (const float*)d_in[14];
    const float* hb2   = (const float*)d_in[15];
    const float* W3d   = (const float*)d_in[16];
    const float* b3d   = (const float*)d_in[17];
    const float* W3r   = (const float*)d_in[18];
    const float* b3r   = (const float*)d_in[19];
    const float* W3v   = (const float*)d_in[20];
    const float* b3v   = (const float*)d_in[21];

    float* out = (float*)d_out;
    // LSTM Pre scratch inside the attn2 region (GAT overwrites it afterwards):
    // 16 blocks * 3 layers * 96*512 floats = 2359296 floats << 25.1M region
    float* SCR = out + 64;

    float* wsf = (float*)d_ws;
    float* XG  = wsf;                   // 16*2048
    float* XL  = wsf + 32768;           // 16*128
    float* HP  = wsf + 34816;           // 3*16*16*64

    lstm_batch_kernel<<<16, 512, 0, stream>>>(x, Wih, Whh, bih, bhh, SCR, XL);
    gat_kernel<<<1536, 256, 0, stream>>>(x, adj, W_emb, b_emb, W1, a1, W2, a2, out + 64, XG);
    head_partial_kernel<<<48, 256, 0, stream>>>(XL, XG, hW1, HP);
    head_final_kernel<<<1, 256, 0, stream>>>(HP, hb1, hW2, hb2, W3d, b3d, W3r, b3r, W3v, b3v, out);
}

// Round 4
// 577.011 us; speedup vs baseline: 1.4813x; 1.0962x over previous
//
#include <hip/hip_runtime.h>
#include <hip/hip_bf16.h>

// ---------------------------------------------------------------------------
// HybridGATLSTM on MI355X — round 4.
//   lstm_batch : 16 blocks (one per batch element); per layer:
//                  proj  = M=96 MFMA GEMM (split-fp16, parallel over t)
//                  rec   = fp32 VALU GEMV: thread=gate-row, Whh row in VGPRs,
//                          h broadcast via LDS, gates exchanged via LDS.
//                MFMA M=1 GEMV was issue-bound (56% MfmaUtil on active CUs,
//                ~2860cyc/step); VALU fp32 floor is 512cyc/step and exact.
//   gat        : unchanged
//   head_*     : unchanged
// Per-block Pre scratch lives in the attn2 region of d_out (GAT runs after).
// ---------------------------------------------------------------------------

typedef _Float16 half8 __attribute__((ext_vector_type(8)));
typedef float floatx4 __attribute__((ext_vector_type(4)));
typedef float float4v __attribute__((ext_vector_type(4)));

#define LOG2E 1.44269504088896f

__device__ __forceinline__ float fast_exp(float x) {
    return __builtin_amdgcn_exp2f(x * LOG2E);
}
__device__ __forceinline__ float sigm(float x) {
    x = fminf(fmaxf(x, -30.f), 30.f);
    return __builtin_amdgcn_rcpf(1.f + __builtin_amdgcn_exp2f(-x * LOG2E));
}
__device__ __forceinline__ float tanhp(float x) {
    x = fminf(fmaxf(x, -15.f), 15.f);
    float e = __builtin_amdgcn_exp2f(-2.f * LOG2E * x);
    return (1.f - e) * __builtin_amdgcn_rcpf(1.f + e);
}
__device__ __forceinline__ void split8v(float4v v0, float4v v1, half8& hi, half8& lo) {
#pragma unroll
    for (int j = 0; j < 4; ++j) {
        _Float16 h = (_Float16)v0[j];
        hi[j] = h; lo[j] = (_Float16)(v0[j] - (float)h);
    }
#pragma unroll
    for (int j = 0; j < 4; ++j) {
        _Float16 h = (_Float16)v1[j];
        hi[4 + j] = h; lo[4 + j] = (_Float16)(v1[j] - (float)h);
    }
}

// ---------------------------------------------------------------------------
// One block per batch element. Layers sequential; no cross-block traffic.
// ---------------------------------------------------------------------------
__global__ __launch_bounds__(512, 2) void lstm_batch_kernel(
    const float* __restrict__ x,     // [16][96][128]
    const float* __restrict__ Wih,   // [3][512][128]
    const float* __restrict__ Whh,   // [3][512][128]
    const float* __restrict__ bih,   // [3][512]
    const float* __restrict__ bhh,   // [3][512]
    float* __restrict__ scratch,     // per block: 3 * 96*512 floats (Pre)
    float* __restrict__ xl_out)      // [16][128]
{
    int b = blockIdx.x;
    float* PreBase = scratch + b * (3 * 96 * 512);

    int tid = threadIdx.x;
    int w = tid >> 6, lane = tid & 63, quad = lane >> 4, sub = lane & 15;

    __shared__ float hbuf[128];        // h_{t-1} (fp32)
    __shared__ float gatebuf[512];     // raw gates for exchange
    __shared__ float Hseq[96 * 132];   // layer output sequence (padded rows)

    for (int layer = 0; layer < 3; ++layer) {
        const float* WihL = Wih + layer * 65536;
        const float* WhhL = Whh + layer * 65536;
        float* Pre = PreBase + layer * (96 * 512);

        // ======== proj GEMM (MFMA, split-fp16): Pre[t][r] = A[t].Wih[r]+bias
        {
            half8 whi[4][4], wlo[4][4];
            float bias[4];
#pragma unroll
            for (int tt = 0; tt < 4; ++tt) {
                int r = tt * 128 + 16 * w + sub;
                bias[tt] = bih[layer * 512 + r] + bhh[layer * 512 + r];
#pragma unroll
                for (int kc = 0; kc < 4; ++kc) {
                    const float4v* p = (const float4v*)(WihL + r * 128 + kc * 32 + quad * 8);
                    split8v(p[0], p[1], whi[tt][kc], wlo[tt][kc]);
                }
            }
            for (int mt = 0; mt < 6; ++mt) {
                half8 ahi[4], alo[4];
                if (layer == 0) {
                    const float* arow = x + b * 12288 + (mt * 16 + sub) * 128;
#pragma unroll
                    for (int kc = 0; kc < 4; ++kc) {
                        const float4v* p = (const float4v*)(arow + kc * 32 + quad * 8);
                        split8v(p[0], p[1], ahi[kc], alo[kc]);
                    }
                } else {
                    const float* arow = Hseq + (mt * 16 + sub) * 132;
#pragma unroll
                    for (int kc = 0; kc < 4; ++kc) {
                        const float4v* p = (const float4v*)(arow + kc * 32 + quad * 8);
                        split8v(p[0], p[1], ahi[kc], alo[kc]);
                    }
                }
                floatx4 acc[4];
#pragma unroll
                for (int tt = 0; tt < 4; ++tt) {
                    floatx4 a = {bias[tt], bias[tt], bias[tt], bias[tt]};
                    acc[tt] = a;
                }
#pragma unroll
                for (int tt = 0; tt < 4; ++tt)
#pragma unroll
                    for (int kc = 0; kc < 4; ++kc) {
                        acc[tt] = __builtin_amdgcn_mfma_f32_16x16x32_f16(ahi[kc], whi[tt][kc], acc[tt], 0, 0, 0);
                        acc[tt] = __builtin_amdgcn_mfma_f32_16x16x32_f16(ahi[kc], wlo[tt][kc], acc[tt], 0, 0, 0);
                        acc[tt] = __builtin_amdgcn_mfma_f32_16x16x32_f16(alo[kc], whi[tt][kc], acc[tt], 0, 0, 0);
                    }
                // store: m(timestep) = mt*16 + quad*4 + reg, row = tt*128+16w+sub
#pragma unroll
                for (int tt = 0; tt < 4; ++tt)
#pragma unroll
                    for (int reg = 0; reg < 4; ++reg)
                        Pre[(mt * 16 + quad * 4 + reg) * 512 + tt * 128 + 16 * w + sub] = acc[tt][reg];
            }
        }

        // ======== recurrence weights: thread tid owns gate-row tid (fp32)
        float4v wrow[32];
        {
            const float4v* wp = (const float4v*)(WhhL + tid * 128);
#pragma unroll
            for (int k = 0; k < 32; ++k) wrow[k] = wp[k];
        }
        if (tid < 128) hbuf[tid] = 0.f;
        float cvar = 0.f;
        __syncthreads();   // Pre stores drained (vmcnt), hbuf zeroed, Hseq free

        // ======== recurrence: 96 steps, fp32 VALU dot + LDS gate exchange
        for (int t = 0; t < 96; ++t) {
            float pre = Pre[t * 512 + tid];   // coalesced, issued early
            const float4v* h4 = (const float4v*)hbuf;
            float4v s = {0.f, 0.f, 0.f, 0.f};
#pragma unroll
            for (int k = 0; k < 32; ++k) s += wrow[k] * h4[k];
            gatebuf[tid] = pre + s.x + s.y + s.z + s.w;
            __syncthreads();   // gates ready; hbuf reads complete

            if (tid < 128) {
                float gi = gatebuf[tid];
                float gf = gatebuf[128 + tid];
                float gg = gatebuf[256 + tid];
                float go = gatebuf[384 + tid];
                float c = sigm(gf) * cvar + sigm(gi) * tanhp(gg);
                cvar = c;
                float h = sigm(go) * tanhp(c);
                hbuf[tid] = h;
                if (layer < 2) Hseq[t * 132 + tid] = h;
                else if (t == 95) xl_out[b * 128 + tid] = h;
            }
            __syncthreads();   // new h visible before next step's reads
        }
        __syncthreads();   // Hseq complete before next layer's proj reads
    }
}

// ---------------------------------------------------------------------------
// GAT (unchanged)
// ---------------------------------------------------------------------------
__global__ __launch_bounds__(256) void gat_kernel(
    const float* __restrict__ x, const float* __restrict__ adj,
    const float* __restrict__ W_emb, const float* __restrict__ b_emb,
    const float* __restrict__ W1, const float* __restrict__ a1,
    const float* __restrict__ W2, const float* __restrict__ a2,
    float* __restrict__ attn_out, float* __restrict__ xg)
{
    int m = blockIdx.x;
    int tid = threadIdx.x;
    __shared__ float xv[128];
    __shared__ unsigned char adjb[128 * 132];
    __shared__ float u1[32], v1[32];
    __shared__ float coef[4];
    __shared__ float s1v[128];
    __shared__ float h2s[128 * 33];
    __shared__ float wh2[128 * 17];
    __shared__ float Lv[128], Rv[128], mx2[128], rd2[128];
    __shared__ float m_h[2][128], d_h[2][128], s_h[2][128];

    if (tid < 128) xv[tid] = x[m * 128 + tid];
    for (int idx = tid; idx < 16384; idx += 256) {
        int i = idx >> 7, j = idx & 127;
        adjb[i * 132 + j] = adj[idx] > 0.f ? 1 : 0;
    }
    if (tid < 32) {
        float su = 0.f, sv = 0.f;
        for (int kk = 0; kk < 32; ++kk) {
            su += W_emb[kk] * W1[kk * 32 + tid];
            sv += b_emb[kk] * W1[kk * 32 + tid];
        }
        u1[tid] = su; v1[tid] = sv;
    }
    __syncthreads();
    if (tid < 4) {
        const float* av = a1 + ((tid >= 2) ? 32 : 0);
        const float* uv = (tid & 1) ? v1 : u1;
        float s = 0.f;
        for (int f = 0; f < 32; ++f) s += uv[f] * av[f];
        coef[tid] = s;
    }
    __syncthreads();
    float cL = coef[0], dL = coef[1], cR = coef[2], dR = coef[3];

    {
        int i = tid & 127, hf = tid >> 7;
        float Li = xv[i] * cL + dL;
        int j0 = hf * 64;
        float mmax = -3.0e38f;
        for (int j = j0; j < j0 + 64; ++j) {
            if (adjb[i * 132 + j]) {
                float e = Li + xv[j] * cR + dR;
                e = e > 0.f ? e : 0.2f * e;
                mmax = fmaxf(mmax, e);
            }
        }
        float den = 0.f, wsum = 0.f;
        for (int j = j0; j < j0 + 64; ++j) {
            if (adjb[i * 132 + j]) {
                float e = Li + xv[j] * cR + dR;
                e = e > 0.f ? e : 0.2f * e;
                float p = fast_exp(e - mmax);
                den += p; wsum += p * xv[j];
            }
        }
        m_h[hf][i] = mmax; d_h[hf][i] = den; s_h[hf][i] = wsum;
    }
    __syncthreads();
    if (tid < 128) {
        int i = tid;
        float m0 = m_h[0][i], m1 = m_h[1][i];
        float mm = fmaxf(m0, m1);
        float sc0 = fast_exp(m0 - mm), sc1 = fast_exp(m1 - mm);
        float den = d_h[0][i] * sc0 + d_h[1][i] * sc1;
        float wsum = s_h[0][i] * sc0 + s_h[1][i] * sc1;
        s1v[i] = wsum / den;
    }
    __syncthreads();
    for (int e = tid; e < 4096; e += 256) {
        int i = e >> 5, f = e & 31;
        float v = s1v[i] * u1[f] + v1[f];
        h2s[i * 33 + f] = v > 0.f ? v : fast_exp(v) - 1.f;
    }
    __syncthreads();
    {
        int i = tid >> 1, g0 = (tid & 1) * 8;
        float accv[8] = {0.f, 0.f, 0.f, 0.f, 0.f, 0.f, 0.f, 0.f};
        for (int f = 0; f < 32; ++f) {
            float hv = h2s[i * 33 + f];
#pragma unroll
            for (int g = 0; g < 8; ++g) accv[g] += hv * W2[f * 16 + g0 + g];
        }
#pragma unroll
        for (int g = 0; g < 8; ++g) wh2[i * 17 + g0 + g] = accv[g];
    }
    __syncthreads();
    {
        int i = tid & 127, which = tid >> 7;
        const float* aa = a2 + which * 16;
        float s = 0.f;
        for (int g = 0; g < 16; ++g) s += wh2[i * 17 + g] * aa[g];
        (which ? Rv : Lv)[i] = s;
    }
    __syncthreads();
    {
        int i = tid & 127, hf = tid >> 7;
        float Li = Lv[i];
        int j0 = hf * 64;
        float mmax = -3.0e38f;
        for (int j = j0; j < j0 + 64; ++j) {
            if (adjb[i * 132 + j]) {
                float e = Li + Rv[j];
                e = e > 0.f ? e : 0.2f * e;
                mmax = fmaxf(mmax, e);
            }
        }
        float den = 0.f;
        for (int j = j0; j < j0 + 64; ++j) {
            if (adjb[i * 132 + j]) {
                float e = Li + Rv[j];
                e = e > 0.f ? e : 0.2f * e;
                den += fast_exp(e - mmax);
            }
        }
        m_h[hf][i] = mmax; d_h[hf][i] = den;
    }
    __syncthreads();
    if (tid < 128) {
        int i = tid;
        float m0 = m_h[0][i], m1 = m_h[1][i];
        float mm = fmaxf(m0, m1);
        float den = d_h[0][i] * fast_exp(m0 - mm) + d_h[1][i] * fast_exp(m1 - mm);
        mx2[i] = mm; rd2[i] = 1.0f / den;
    }
    __syncthreads();
    float* aout = attn_out + m * 16384;
    for (int idx = tid; idx < 16384; idx += 256) {
        int i = idx >> 7, j = idx & 127;
        float p = 0.f;
        if (adjb[i * 132 + j]) {
            float e = Lv[i] + Rv[j];
            e = e > 0.f ? e : 0.2f * e;
            p = fast_exp(e - mx2[i]) * rd2[i];
        }
        aout[idx] = p;
    }
    if (m % 96 == 95) {
        int b = m / 96;
        int i = tid >> 1, g0 = (tid & 1) * 8;
        float accv[8] = {0.f, 0.f, 0.f, 0.f, 0.f, 0.f, 0.f, 0.f};
        for (int j = 0; j < 128; ++j) {
            float p = 0.f;
            if (adjb[i * 132 + j]) {
                float e = Lv[i] + Rv[j];
                e = e > 0.f ? e : 0.2f * e;
                p = fast_exp(e - mx2[i]) * rd2[i];
            }
#pragma unroll
            for (int g = 0; g < 8; ++g) accv[g] += p * wh2[j * 17 + g0 + g];
        }
#pragma unroll
        for (int g = 0; g < 8; ++g) xg[b * 2048 + i * 16 + g0 + g] = accv[g];
    }
}

// ---------------------------------------------------------------------------
// Heads (unchanged)
// ---------------------------------------------------------------------------
__global__ __launch_bounds__(256) void head_partial_kernel(
    const float* __restrict__ xl, const float* __restrict__ xg,
    const float* __restrict__ W1, float* __restrict__ hp)
{
    int k = blockIdx.x >> 4, chunk = blockIdx.x & 15;
    int d = threadIdx.x & 63, bg = threadIdx.x >> 6;
    float acc[4] = {0.f, 0.f, 0.f, 0.f};
    int c0 = chunk * 136;
    for (int cc = c0; cc < c0 + 136; ++cc) {
        float wv = W1[(k * 2176 + cc) * 64 + d];
#pragma unroll
        for (int u = 0; u < 4; ++u) {
            int b = bg * 4 + u;
            float cv = (cc < 128) ? xl[b * 128 + cc] : xg[b * 2048 + cc - 128];
            acc[u] += wv * cv;
        }
    }
#pragma unroll
    for (int u = 0; u < 4; ++u)
        hp[(((k * 16 + chunk) * 16) + bg * 4 + u) * 64 + d] = acc[u];
}

__global__ __launch_bounds__(256) void head_final_kernel(
    const float* __restrict__ hp, const float* __restrict__ b1,
    const float* __restrict__ W2, const float* __restrict__ b2,
    const float* __restrict__ W3d, const float* __restrict__ b3d,
    const float* __restrict__ W3r, const float* __restrict__ b3r,
    const float* __restrict__ W3v, const float* __restrict__ b3v,
    float* __restrict__ out)
{
    __shared__ float h1s[3 * 16 * 64];
    __shared__ float h2s[3 * 16 * 32];
    int tid = threadIdx.x;
    for (int o = tid; o < 3072; o += 256) {
        int k = o >> 10, rem = o & 1023, b = rem >> 6, d = rem & 63;
        float s = b1[k * 64 + d];
        for (int ch = 0; ch < 16; ++ch)
            s += hp[(((k * 16 + ch) * 16) + b) * 64 + d];
        h1s[o] = fmaxf(s, 0.f);
    }
    __syncthreads();
    for (int o = tid; o < 1536; o += 256) {
        int k = o >> 9, rem = o & 511, b = rem >> 5, e = rem & 31;
        float s = b2[k * 32 + e];
        for (int dd = 0; dd < 64; ++dd)
            s += h1s[(k * 16 + b) * 64 + dd] * W2[(k * 64 + dd) * 32 + e];
        h2s[o] = fmaxf(s, 0.f);
    }
    __syncthreads();
    if (tid < 64) {
        if (tid < 16) {
            int b = tid; float s = b3d[0];
            for (int e = 0; e < 32; ++e) s += h2s[b * 32 + e] * W3d[e];
            out[b] = s;
        } else if (tid < 32) {
            int b = tid - 16; float s = b3r[0];
            for (int e = 0; e < 32; ++e) s += h2s[(16 + b) * 32 + e] * W3r[e];
            out[16 + b] = s;
        } else {
            int b = (tid - 32) >> 1, j = tid & 1; float s = b3v[j];
            for (int e = 0; e < 32; ++e) s += h2s[(32 + b) * 32 + e] * W3v[e * 2 + j];
            out[32 + b * 2 + j] = s;
        }
    }
}

// ---------------------------------------------------------------------------
extern "C" void kernel_launch(void* const* d_in, const int* in_sizes, int n_in,
                              void* d_out, int out_size, void* d_ws, size_t ws_size,
                              hipStream_t stream)
{
    const float* x     = (const float*)d_in[0];
    const float* adj   = (const float*)d_in[1];
    const float* W_emb = (const float*)d_in[2];
    const float* b_emb = (const float*)d_in[3];
    const float* W1    = (const float*)d_in[4];
    const float* a1    = (const float*)d_in[5];
    const float* W2    = (const float*)d_in[6];
    const float* a2    = (const float*)d_in[7];
    const float* Wih   = (const float*)d_in[8];
    const float* Whh   = (const float*)d_in[9];
    const float* bih   = (const float*)d_in[10];
    const float* bhh   = (const float*)d_in[11];
    const float* hW1   = (const float*)d_in[12];
    const float* hb1   = (const float*)d_in[13];
    const float* hW2   = (const float*)d_in[14];
    const float* hb2   = (const float*)d_in[15];
    const float* W3d   = (const float*)d_in[16];
    const float* b3d   = (const float*)d_in[17];
    const float* W3r   = (const float*)d_in[18];
    const float* b3r   = (const float*)d_in[19];
    const float* W3v   = (const float*)d_in[20];
    const float* b3v   = (const float*)d_in[21];

    float* out = (float*)d_out;
    // LSTM Pre scratch inside the attn2 region (GAT overwrites it afterwards):
    // 16 blocks * 3 layers * 96*512 floats = 2359296 floats << 25.1M region
    float* SCR = out + 64;

    float* wsf = (float*)d_ws;
    float* XG  = wsf;                   // 16*2048
    float* XL  = wsf + 32768;           // 16*128
    float* HP  = wsf + 34816;           // 3*16*16*64

    lstm_batch_kernel<<<16, 512, 0, stream>>>(x, Wih, Whh, bih, bhh, SCR, XL);
    gat_kernel<<<1536, 256, 0, stream>>>(x, adj, W_emb, b_emb, W1, a1, W2, a2, out + 64, XG);
    head_partial_kernel<<<48, 256, 0, stream>>>(XL, XG, hW1, HP);
    head_final_kernel<<<1, 256, 0, stream>>>(HP, hb1, hW2, hb2, W3d, b3d, W3r, b3r, W3v, b3v, out);
}